// Round 1
// baseline (413.497 us; speedup 1.0000x reference)
//
#include <hip/hip_runtime.h>
#include <cstdint>

#define DEVI __device__ __forceinline__

typedef __bf16 bf16;
typedef __bf16 bf16x8 __attribute__((ext_vector_type(8)));
typedef __bf16 bf16x4 __attribute__((ext_vector_type(4)));
typedef float floatx4 __attribute__((ext_vector_type(4)));

constexpr int BATCH = 16, SEQ = 2048, DM = 256, DI = 512;
constexpr int M = BATCH * SEQ;   // 32768 rows
constexpr int NC = 16;           // scan chunks per sequence
constexpr int CL = SEQ / NC;     // 128 steps per chunk
static_assert(NC * CL == SEQ, "chunking");

// ---- async global->LDS (16B per lane, wave-uniform base + lane*16) ----
DEVI void gl2lds16(const void* g, void* l) {
  __builtin_amdgcn_global_load_lds(
      (const __attribute__((address_space(1))) unsigned int*)(uintptr_t)g,
      (__attribute__((address_space(3))) unsigned int*)(unsigned int)(uintptr_t)l,
      16, 0, 0);
}

DEVI float sigmoidf_(float x) { return 1.f / (1.f + __expf(-x)); }

// =================== prep: weights fp32 -> bf16, A = -exp(A_log) ===================
__global__ __launch_bounds__(256) void prep_kernel(
    const float* __restrict__ w1, const float* __restrict__ wx,
    const float* __restrict__ wo, const float* __restrict__ alog,
    bf16* __restrict__ w1b, bf16* __restrict__ wxb, bf16* __restrict__ wob,
    float* __restrict__ An) {
  constexpr int n1 = 1024 * 256, n2 = 48 * 512, n3 = 256 * 512, n4 = 512 * 16;
  int i = blockIdx.x * 256 + threadIdx.x;
  if (i < n1) w1b[i] = (bf16)w1[i];
  else if (i < n1 + n2) wxb[i - n1] = (bf16)wx[i - n1];
  else if (i < n1 + n2 + n3) wob[i - n1 - n2] = (bf16)wo[i - n1 - n2];
  else if (i < n1 + n2 + n3 + n4) An[i - n1 - n2 - n3] = -__expf(alog[i - n1 - n2 - n3]);
}

// =================== LayerNorm: one wave per 256-col row, bf16 out ===================
__global__ __launch_bounds__(256) void ln_kernel(
    const float* __restrict__ x, const float* __restrict__ w,
    const float* __restrict__ b, bf16* __restrict__ xn) {
  const int row = blockIdx.x * 4 + (threadIdx.x >> 6);
  const int lane = threadIdx.x & 63;
  const float4 v = ((const float4*)(x + (size_t)row * DM))[lane];
  float s = v.x + v.y + v.z + v.w;
  float s2 = v.x * v.x + v.y * v.y + v.z * v.z + v.w * v.w;
#pragma unroll
  for (int m = 1; m < 64; m <<= 1) { s += __shfl_xor(s, m); s2 += __shfl_xor(s2, m); }
  const float mu = s * (1.f / DM);
  const float var = s2 * (1.f / DM) - mu * mu;
  const float rs = rsqrtf(var + 1e-5f);
  const float4 wv = ((const float4*)w)[lane];
  const float4 bv = ((const float4*)b)[lane];
  bf16x4 o;
  o[0] = (bf16)((v.x - mu) * rs * wv.x + bv.x);
  o[1] = (bf16)((v.y - mu) * rs * wv.y + bv.y);
  o[2] = (bf16)((v.z - mu) * rs * wv.z + bv.z);
  o[3] = (bf16)((v.w - mu) * rs * wv.w + bv.w);
  *(bf16x4*)(xn + (size_t)row * DM + lane * 4) = o;
}

// =================== NT bf16 GEMM: C[M,N] = A[M,K] * W[N,K]^T (m97 structure) ===================
// 128x128 tile, BK=32, 4 waves each 64x64 (4x4 MFMA 16x16x32).
template <int N, int K, bool OUT_BF16, bool RESID>
__global__ __launch_bounds__(256) void gemm_nt(const bf16* __restrict__ A,
                                               const bf16* __restrict__ W,
                                               void* __restrict__ out,
                                               const float* __restrict__ resid) {
  constexpr int BK = 32;
  __shared__ __align__(16) bf16 lA[128 * BK];
  __shared__ __align__(16) bf16 lB[128 * BK];
  const int tid = threadIdx.x;
  const int wave = tid >> 6, lane = tid & 63;
  const int bm = blockIdx.x * 128, bn = blockIdx.y * 128;
  const int wm = (wave >> 1) * 64, wn = (wave & 1) * 64;
  const int q = lane >> 4, r = lane & 15;
  floatx4 acc[4][4] = {};
  const int c0 = wave * 64 + lane;  // staging chunk ids: c0 and c0+256 (of 512)
  const int row0 = c0 >> 2, kp = (c0 & 3) * 8;
  for (int k0 = 0; k0 < K; k0 += BK) {
    gl2lds16(A + (size_t)(bm + row0) * K + k0 + kp, lA + c0 * 8);
    gl2lds16(A + (size_t)(bm + row0 + 64) * K + k0 + kp, lA + (c0 + 256) * 8);
    gl2lds16(W + (size_t)(bn + row0) * K + k0 + kp, lB + c0 * 8);
    gl2lds16(W + (size_t)(bn + row0 + 64) * K + k0 + kp, lB + (c0 + 256) * 8);
    __syncthreads();
    bf16x8 af[4], bfr[4];
#pragma unroll
    for (int i = 0; i < 4; i++) af[i] = *(const bf16x8*)&lA[(wm + i * 16 + r) * BK + q * 8];
#pragma unroll
    for (int j = 0; j < 4; j++) bfr[j] = *(const bf16x8*)&lB[(wn + j * 16 + r) * BK + q * 8];
#pragma unroll
    for (int i = 0; i < 4; i++)
#pragma unroll
      for (int j = 0; j < 4; j++)
        acc[i][j] = __builtin_amdgcn_mfma_f32_16x16x32_bf16(af[i], bfr[j], acc[i][j], 0, 0, 0);
    __syncthreads();
  }
  // C/D: col = lane&15, row = (lane>>4)*4 + t  [m89/m91 verified]
#pragma unroll
  for (int i = 0; i < 4; i++)
#pragma unroll
    for (int j = 0; j < 4; j++)
#pragma unroll
      for (int t = 0; t < 4; t++) {
        const int row = bm + wm + i * 16 + q * 4 + t;
        const int col = bn + wn + j * 16 + r;
        const size_t idx = (size_t)row * N + col;
        float v = acc[i][j][t];
        if constexpr (OUT_BF16) {
          ((bf16*)out)[idx] = (bf16)v;
        } else {
          if constexpr (RESID) v += resid[idx];
          ((float*)out)[idx] = v;
        }
      }
}

// =================== causal depthwise conv(4) + SiLU ===================
__global__ __launch_bounds__(256) void conv_silu(const bf16* __restrict__ xz,
                                                 const float* __restrict__ cw,
                                                 const float* __restrict__ cb,
                                                 bf16* __restrict__ xc) {
  const int idx = blockIdx.x * 256 + threadIdx.x;  // over M*DI
  const int e = idx & (DI - 1);
  const int pos = idx >> 9;
  const int l = pos & (SEQ - 1);
  const float4 w4 = ((const float4*)cw)[e];
  const float wj[4] = {w4.x, w4.y, w4.z, w4.w};
  float acc = cb[e];
#pragma unroll
  for (int j = 0; j < 4; j++) {
    const int li = l - 3 + j;
    if (li >= 0) acc += (float)xz[((size_t)pos - (3 - j)) * 1024 + e] * wj[j];
  }
  xc[(size_t)pos * DI + e] = (bf16)(acc * sigmoidf_(acc));
}

// =================== x_proj: dbc[M,48] = xc[M,512] * Wx[48,512]^T (W resident in LDS) ===================
__global__ __launch_bounds__(256) void gemm_xproj(const bf16* __restrict__ A,
                                                  const bf16* __restrict__ W,
                                                  float* __restrict__ out) {
  constexpr int K = DI;
  __shared__ __align__(16) bf16 lW[48 * K];    // 49152 B
  __shared__ __align__(16) bf16 lA[128 * 32];  // 8192 B
  const int tid = threadIdx.x;
  const int wave = tid >> 6, lane = tid & 63;
  const int bm = blockIdx.x * 128;
  const int q = lane >> 4, r = lane & 15;
#pragma unroll
  for (int rd = 0; rd < 12; rd++) {  // 3072 chunks of 16B
    const int c = rd * 256 + tid;
    gl2lds16((const char*)W + (size_t)c * 16, (char*)lW + (size_t)c * 16);
  }
  const int c0 = wave * 64 + lane;
  const int row0 = c0 >> 2, kp = (c0 & 3) * 8;
  const int wm = wave * 32;
  floatx4 acc[2][3] = {};
  for (int k0 = 0; k0 < K; k0 += 32) {
    gl2lds16(A + (size_t)(bm + row0) * K + k0 + kp, lA + c0 * 8);
    gl2lds16(A + (size_t)(bm + row0 + 64) * K + k0 + kp, lA + (c0 + 256) * 8);
    __syncthreads();
    bf16x8 af[2], bfr[3];
#pragma unroll
    for (int i = 0; i < 2; i++) af[i] = *(const bf16x8*)&lA[(wm + i * 16 + r) * 32 + q * 8];
#pragma unroll
    for (int j = 0; j < 3; j++) bfr[j] = *(const bf16x8*)&lW[(j * 16 + r) * K + k0 + q * 8];
#pragma unroll
    for (int i = 0; i < 2; i++)
#pragma unroll
      for (int j = 0; j < 3; j++)
        acc[i][j] = __builtin_amdgcn_mfma_f32_16x16x32_bf16(af[i], bfr[j], acc[i][j], 0, 0, 0);
    __syncthreads();
  }
#pragma unroll
  for (int i = 0; i < 2; i++)
#pragma unroll
    for (int j = 0; j < 3; j++)
#pragma unroll
      for (int t = 0; t < 4; t++)
        out[(size_t)(bm + wm + i * 16 + q * 4 + t) * 48 + j * 16 + r] = acc[i][j][t];
}

// =================== dt_proj (K=16) + softplus -> bf16 ===================
__global__ __launch_bounds__(256) void dtproj_kernel(const float* __restrict__ dbc,
                                                     const float* __restrict__ dtw,
                                                     const float* __restrict__ dtb,
                                                     bf16* __restrict__ dt) {
  __shared__ __align__(16) float sd[64 * 16];
  const int tid = threadIdx.x;
  const int p0 = blockIdx.x * 64;
  const int e = blockIdx.y * 256 + tid;
  {
    const int rowi = tid >> 2, coli = (tid & 3) * 4;
    *(float4*)&sd[rowi * 16 + coli] = *(const float4*)(dbc + (size_t)(p0 + rowi) * 48 + coli);
  }
  float w[16];
#pragma unroll
  for (int s = 0; s < 16; s += 4) {
    float4 t4 = *(const float4*)(dtw + (size_t)e * 16 + s);
    w[s] = t4.x; w[s + 1] = t4.y; w[s + 2] = t4.z; w[s + 3] = t4.w;
  }
  const float bias = dtb[e];
  __syncthreads();
  for (int p = 0; p < 64; p++) {
    float s = bias;
#pragma unroll
    for (int r2 = 0; r2 < 16; r2++) s += sd[p * 16 + r2] * w[r2];
    const float sp = (s > 15.f) ? s : __logf(1.f + __expf(s));
    dt[(size_t)(p0 + p) * DI + e] = (bf16)sp;
  }
}

// =================== scan pass1: per-chunk aggregates (U from h0=0, sum_dt) ===================
__global__ __launch_bounds__(256) void scan_pass1(const bf16* __restrict__ dt,
                                                  const bf16* __restrict__ xc,
                                                  const float* __restrict__ dbc,
                                                  const float* __restrict__ An,
                                                  float* __restrict__ U,
                                                  float* __restrict__ SD) {
  const int e = blockIdx.x * 256 + threadIdx.x;
  const int ch = blockIdx.y, b = blockIdx.z;
  float A[16], h[16];
#pragma unroll
  for (int s = 0; s < 16; s += 4) {
    float4 a4 = *(const float4*)(An + (size_t)e * 16 + s);
    A[s] = a4.x; A[s + 1] = a4.y; A[s + 2] = a4.z; A[s + 3] = a4.w;
  }
#pragma unroll
  for (int s = 0; s < 16; s++) h[s] = 0.f;
  float sdt = 0.f;
  const size_t posBase = (size_t)b * SEQ + (size_t)ch * CL;
  for (int il = 0; il < CL; il++) {
    const size_t pos = posBase + il;
    const float dtv = (float)dt[pos * DI + e];
    const float xv = (float)xc[pos * DI + e];
    const float* bc = dbc + pos * 48 + 16;
    float Bv[16];
#pragma unroll
    for (int s = 0; s < 16; s += 4) {
      float4 b4 = *(const float4*)(bc + s);
      Bv[s] = b4.x; Bv[s + 1] = b4.y; Bv[s + 2] = b4.z; Bv[s + 3] = b4.w;
    }
    const float dtx = dtv * xv;
    sdt += dtv;
#pragma unroll
    for (int s = 0; s < 16; s++) h[s] = __expf(dtv * A[s]) * h[s] + dtx * Bv[s];
  }
  float* up = U + ((size_t)(b * NC + ch) * DI + e) * 16;
#pragma unroll
  for (int s = 0; s < 16; s += 4) {
    float4 o; o.x = h[s]; o.y = h[s + 1]; o.z = h[s + 2]; o.w = h[s + 3];
    *(float4*)(up + s) = o;
  }
  SD[(size_t)(b * NC + ch) * DI + e] = sdt;
}

// =================== scan pass2: combine chunk aggregates; U[c] := h0 entering chunk c ===================
__global__ __launch_bounds__(256) void scan_pass2(const float* __restrict__ SD,
                                                  float* U,
                                                  const float* __restrict__ An) {
  const int t = blockIdx.x * 256 + threadIdx.x;  // B*DI threads
  const int e = t & (DI - 1);
  const int b = t >> 9;
  float A[16], h[16];
#pragma unroll
  for (int s = 0; s < 16; s += 4) {
    float4 a4 = *(const float4*)(An + (size_t)e * 16 + s);
    A[s] = a4.x; A[s + 1] = a4.y; A[s + 2] = a4.z; A[s + 3] = a4.w;
  }
#pragma unroll
  for (int s = 0; s < 16; s++) h[s] = 0.f;
  for (int c = 0; c < NC; c++) {
    const size_t base = ((size_t)(b * NC + c) * DI + e) * 16;
    const float sdv = SD[(size_t)(b * NC + c) * DI + e];
    float u[16];
#pragma unroll
    for (int s = 0; s < 16; s += 4) {
      float4 u4 = *(const float4*)(U + base + s);
      u[s] = u4.x; u[s + 1] = u4.y; u[s + 2] = u4.z; u[s + 3] = u4.w;
    }
#pragma unroll
    for (int s = 0; s < 16; s++) {
      const float h0 = h[s];
      h[s] = __expf(A[s] * sdv) * h0 + u[s];
      u[s] = h0;
    }
#pragma unroll
    for (int s = 0; s < 16; s += 4) {
      float4 o; o.x = u[s]; o.y = u[s + 1]; o.z = u[s + 2]; o.w = u[s + 3];
      *(float4*)(U + base + s) = o;
    }
  }
}

// =================== scan pass3: replay chunk from true h0, emit gated y (yg aliases dt!) ===================
__global__ __launch_bounds__(256) void scan_pass3(const bf16* dt,
                                                  const bf16* __restrict__ xc,
                                                  const bf16* __restrict__ xz,
                                                  const float* __restrict__ dbc,
                                                  const float* __restrict__ An,
                                                  const float* __restrict__ H0,
                                                  const float* __restrict__ Dp,
                                                  bf16* yg) {
  const int e = blockIdx.x * 256 + threadIdx.x;
  const int ch = blockIdx.y, b = blockIdx.z;
  float A[16], h[16];
#pragma unroll
  for (int s = 0; s < 16; s += 4) {
    float4 a4 = *(const float4*)(An + (size_t)e * 16 + s);
    A[s] = a4.x; A[s + 1] = a4.y; A[s + 2] = a4.z; A[s + 3] = a4.w;
  }
  const float* hp = H0 + ((size_t)(b * NC + ch) * DI + e) * 16;
#pragma unroll
  for (int s = 0; s < 16; s += 4) {
    float4 h4 = *(const float4*)(hp + s);
    h[s] = h4.x; h[s + 1] = h4.y; h[s + 2] = h4.z; h[s + 3] = h4.w;
  }
  const float Dv = Dp[e];
  const size_t posBase = (size_t)b * SEQ + (size_t)ch * CL;
  for (int il = 0; il < CL; il++) {
    const size_t pos = posBase + il;
    const float dtv = (float)dt[pos * DI + e];
    const float xv = (float)xc[pos * DI + e];
    const float zv = (float)xz[pos * 1024 + DI + e];
    const float* bc = dbc + pos * 48 + 16;
    float Bv[16], Cv[16];
#pragma unroll
    for (int s = 0; s < 16; s += 4) {
      float4 b4 = *(const float4*)(bc + s);
      Bv[s] = b4.x; Bv[s + 1] = b4.y; Bv[s + 2] = b4.z; Bv[s + 3] = b4.w;
      float4 c4 = *(const float4*)(bc + 16 + s);
      Cv[s] = c4.x; Cv[s + 1] = c4.y; Cv[s + 2] = c4.z; Cv[s + 3] = c4.w;
    }
    const float dtx = dtv * xv;
    float y = 0.f;
#pragma unroll
    for (int s = 0; s < 16; s++) {
      h[s] = __expf(dtv * A[s]) * h[s] + dtx * Bv[s];
      y += h[s] * Cv[s];
    }
    const float yv = (y + Dv * xv) * zv * sigmoidf_(zv);
    yg[pos * DI + e] = (bf16)yv;  // same index this thread just read dt from — safe in-place
  }
}

// =================== host ===================
extern "C" void kernel_launch(void* const* d_in, const int* in_sizes, int n_in,
                              void* d_out, int out_size, void* d_ws, size_t ws_size,
                              hipStream_t stream) {
  const float* x = (const float*)d_in[0];
  const float* ln_w = (const float*)d_in[1];
  const float* ln_b = (const float*)d_in[2];
  const float* w_in = (const float*)d_in[3];
  const float* conv_w = (const float*)d_in[4];
  const float* conv_b = (const float*)d_in[5];
  const float* w_x = (const float*)d_in[6];
  const float* w_dt = (const float*)d_in[7];
  const float* b_dt = (const float*)d_in[8];
  const float* a_log = (const float*)d_in[9];
  const float* d_par = (const float*)d_in[10];
  const float* w_out = (const float*)d_in[11];

  char* ws = (char*)d_ws;
  size_t off = 0;
  auto alloc = [&](size_t bytes) {
    void* p = ws + off;
    off = (off + bytes + 255) & ~(size_t)255;
    return p;
  };
  bf16* xn = (bf16*)alloc((size_t)M * DM * 2);          // 16.8 MB
  bf16* xzb = (bf16*)alloc((size_t)M * 1024 * 2);       // 67.1 MB
  bf16* xcb = (bf16*)alloc((size_t)M * DI * 2);         // 33.6 MB
  float* dbc = (float*)alloc((size_t)M * 48 * 4);       // 6.3 MB
  bf16* dtb_ = (bf16*)alloc((size_t)M * DI * 2);        // 33.6 MB (becomes yg in pass3)
  float* U = (float*)alloc((size_t)BATCH * NC * DI * 16 * 4);  // 8.4 MB
  float* SD = (float*)alloc((size_t)BATCH * NC * DI * 4);      // 0.5 MB
  bf16* w1b = (bf16*)alloc(1024 * 256 * 2);
  bf16* wxb = (bf16*)alloc(48 * 512 * 2);
  bf16* wob = (bf16*)alloc(256 * 512 * 2);
  float* An = (float*)alloc(512 * 16 * 4);

  prep_kernel<<<dim3(1664), dim3(256), 0, stream>>>(w_in, w_x, w_out, a_log, w1b, wxb, wob, An);
  ln_kernel<<<dim3(M / 4), dim3(256), 0, stream>>>(x, ln_w, ln_b, xn);
  gemm_nt<1024, 256, true, false><<<dim3(M / 128, 8), dim3(256), 0, stream>>>(xn, w1b, (void*)xzb, nullptr);
  conv_silu<<<dim3((size_t)M * DI / 256), dim3(256), 0, stream>>>(xzb, conv_w, conv_b, xcb);
  gemm_xproj<<<dim3(M / 128), dim3(256), 0, stream>>>(xcb, wxb, dbc);
  dtproj_kernel<<<dim3(M / 64, 2), dim3(256), 0, stream>>>(dbc, w_dt, b_dt, dtb_);
  scan_pass1<<<dim3(2, NC, BATCH), dim3(256), 0, stream>>>(dtb_, xcb, dbc, An, U, SD);
  scan_pass2<<<dim3(BATCH * DI / 256), dim3(256), 0, stream>>>(SD, U, An);
  scan_pass3<<<dim3(2, NC, BATCH), dim3(256), 0, stream>>>(dtb_, xcb, xzb, dbc, An, U, d_par, dtb_);
  gemm_nt<256, 512, false, true><<<dim3(M / 128, 2), dim3(256), 0, stream>>>(dtb_, wob, d_out, x);
}

// Round 2
// 382.323 us; speedup vs baseline: 1.0815x; 1.0815x over previous
//
#include <hip/hip_runtime.h>
#include <cstdint>

#define DEVI __device__ __forceinline__

typedef __bf16 bf16;
typedef __bf16 bf16x8 __attribute__((ext_vector_type(8)));
typedef __bf16 bf16x4 __attribute__((ext_vector_type(4)));
typedef float floatx4 __attribute__((ext_vector_type(4)));

constexpr int BATCH = 16, SEQ = 2048, DM = 256, DI = 512;
constexpr int M = BATCH * SEQ;   // 32768 rows
constexpr int NC = 64;           // scan chunks per sequence (R2: 16->64 for occupancy)
constexpr int CL = SEQ / NC;     // 32 steps per chunk
static_assert(NC * CL == SEQ, "chunking");

// ---- async global->LDS (16B per lane, wave-uniform base + lane*16) ----
DEVI void gl2lds16(const void* g, void* l) {
  __builtin_amdgcn_global_load_lds(
      (const __attribute__((address_space(1))) unsigned int*)(uintptr_t)g,
      (__attribute__((address_space(3))) unsigned int*)(unsigned int)(uintptr_t)l,
      16, 0, 0);
}

DEVI float sigmoidf_(float x) { return 1.f / (1.f + __expf(-x)); }

// =================== prep: weights fp32 -> bf16, A = -exp(A_log) ===================
__global__ __launch_bounds__(256) void prep_kernel(
    const float* __restrict__ w1, const float* __restrict__ wx,
    const float* __restrict__ wo, const float* __restrict__ alog,
    bf16* __restrict__ w1b, bf16* __restrict__ wxb, bf16* __restrict__ wob,
    float* __restrict__ An) {
  constexpr int n1 = 1024 * 256, n2 = 48 * 512, n3 = 256 * 512, n4 = 512 * 16;
  int i = blockIdx.x * 256 + threadIdx.x;
  if (i < n1) w1b[i] = (bf16)w1[i];
  else if (i < n1 + n2) wxb[i - n1] = (bf16)wx[i - n1];
  else if (i < n1 + n2 + n3) wob[i - n1 - n2] = (bf16)wo[i - n1 - n2];
  else if (i < n1 + n2 + n3 + n4) An[i - n1 - n2 - n3] = -__expf(alog[i - n1 - n2 - n3]);
}

// =================== LayerNorm: one wave per 256-col row, bf16 out ===================
__global__ __launch_bounds__(256) void ln_kernel(
    const float* __restrict__ x, const float* __restrict__ w,
    const float* __restrict__ b, bf16* __restrict__ xn) {
  const int row = blockIdx.x * 4 + (threadIdx.x >> 6);
  const int lane = threadIdx.x & 63;
  const float4 v = ((const float4*)(x + (size_t)row * DM))[lane];
  float s = v.x + v.y + v.z + v.w;
  float s2 = v.x * v.x + v.y * v.y + v.z * v.z + v.w * v.w;
#pragma unroll
  for (int m = 1; m < 64; m <<= 1) { s += __shfl_xor(s, m); s2 += __shfl_xor(s2, m); }
  const float mu = s * (1.f / DM);
  const float var = s2 * (1.f / DM) - mu * mu;
  const float rs = rsqrtf(var + 1e-5f);
  const float4 wv = ((const float4*)w)[lane];
  const float4 bv = ((const float4*)b)[lane];
  bf16x4 o;
  o[0] = (bf16)((v.x - mu) * rs * wv.x + bv.x);
  o[1] = (bf16)((v.y - mu) * rs * wv.y + bv.y);
  o[2] = (bf16)((v.z - mu) * rs * wv.z + bv.z);
  o[3] = (bf16)((v.w - mu) * rs * wv.w + bv.w);
  *(bf16x4*)(xn + (size_t)row * DM + lane * 4) = o;
}

// =================== NT bf16 GEMM: C[M,N] = A[M,K] * W[N,K]^T (m97 structure) ===================
// 128x128 tile, BK=32, 4 waves each 64x64 (4x4 MFMA 16x16x32).
template <int N, int K, bool OUT_BF16, bool RESID>
__global__ __launch_bounds__(256) void gemm_nt(const bf16* __restrict__ A,
                                               const bf16* __restrict__ W,
                                               void* __restrict__ out,
                                               const float* __restrict__ resid) {
  constexpr int BK = 32;
  __shared__ __align__(16) bf16 lA[128 * BK];
  __shared__ __align__(16) bf16 lB[128 * BK];
  const int tid = threadIdx.x;
  const int wave = tid >> 6, lane = tid & 63;
  const int bm = blockIdx.x * 128, bn = blockIdx.y * 128;
  const int wm = (wave >> 1) * 64, wn = (wave & 1) * 64;
  const int q = lane >> 4, r = lane & 15;
  floatx4 acc[4][4] = {};
  const int c0 = wave * 64 + lane;  // staging chunk ids: c0 and c0+256 (of 512)
  const int row0 = c0 >> 2, kp = (c0 & 3) * 8;
  for (int k0 = 0; k0 < K; k0 += BK) {
    gl2lds16(A + (size_t)(bm + row0) * K + k0 + kp, lA + c0 * 8);
    gl2lds16(A + (size_t)(bm + row0 + 64) * K + k0 + kp, lA + (c0 + 256) * 8);
    gl2lds16(W + (size_t)(bn + row0) * K + k0 + kp, lB + c0 * 8);
    gl2lds16(W + (size_t)(bn + row0 + 64) * K + k0 + kp, lB + (c0 + 256) * 8);
    __syncthreads();
    bf16x8 af[4], bfr[4];
#pragma unroll
    for (int i = 0; i < 4; i++) af[i] = *(const bf16x8*)&lA[(wm + i * 16 + r) * BK + q * 8];
#pragma unroll
    for (int j = 0; j < 4; j++) bfr[j] = *(const bf16x8*)&lB[(wn + j * 16 + r) * BK + q * 8];
#pragma unroll
    for (int i = 0; i < 4; i++)
#pragma unroll
      for (int j = 0; j < 4; j++)
        acc[i][j] = __builtin_amdgcn_mfma_f32_16x16x32_bf16(af[i], bfr[j], acc[i][j], 0, 0, 0);
    __syncthreads();
  }
  // C/D: col = lane&15, row = (lane>>4)*4 + t  [m89/m91 verified]
#pragma unroll
  for (int i = 0; i < 4; i++)
#pragma unroll
    for (int j = 0; j < 4; j++)
#pragma unroll
      for (int t = 0; t < 4; t++) {
        const int row = bm + wm + i * 16 + q * 4 + t;
        const int col = bn + wn + j * 16 + r;
        const size_t idx = (size_t)row * N + col;
        float v = acc[i][j][t];
        if constexpr (OUT_BF16) {
          ((bf16*)out)[idx] = (bf16)v;
        } else {
          if constexpr (RESID) v += resid[idx];
          ((float*)out)[idx] = v;
        }
      }
}

// =================== causal depthwise conv(4) + SiLU ===================
__global__ __launch_bounds__(256) void conv_silu(const bf16* __restrict__ xz,
                                                 const float* __restrict__ cw,
                                                 const float* __restrict__ cb,
                                                 bf16* __restrict__ xc) {
  const int idx = blockIdx.x * 256 + threadIdx.x;  // over M*DI
  const int e = idx & (DI - 1);
  const int pos = idx >> 9;
  const int l = pos & (SEQ - 1);
  const float4 w4 = ((const float4*)cw)[e];
  const float wj[4] = {w4.x, w4.y, w4.z, w4.w};
  float acc = cb[e];
#pragma unroll
  for (int j = 0; j < 4; j++) {
    const int li = l - 3 + j;
    if (li >= 0) acc += (float)xz[((size_t)pos - (3 - j)) * 1024 + e] * wj[j];
  }
  xc[(size_t)pos * DI + e] = (bf16)(acc * sigmoidf_(acc));
}

// =================== x_proj: dbc[M,48] = xc[M,512] * Wx[48,512]^T (W resident in LDS) ===================
__global__ __launch_bounds__(256) void gemm_xproj(const bf16* __restrict__ A,
                                                  const bf16* __restrict__ W,
                                                  float* __restrict__ out) {
  constexpr int K = DI;
  __shared__ __align__(16) bf16 lW[48 * K];    // 49152 B
  __shared__ __align__(16) bf16 lA[128 * 32];  // 8192 B
  const int tid = threadIdx.x;
  const int wave = tid >> 6, lane = tid & 63;
  const int bm = blockIdx.x * 128;
  const int q = lane >> 4, r = lane & 15;
#pragma unroll
  for (int rd = 0; rd < 12; rd++) {  // 3072 chunks of 16B
    const int c = rd * 256 + tid;
    gl2lds16((const char*)W + (size_t)c * 16, (char*)lW + (size_t)c * 16);
  }
  const int c0 = wave * 64 + lane;
  const int row0 = c0 >> 2, kp = (c0 & 3) * 8;
  const int wm = wave * 32;
  floatx4 acc[2][3] = {};
  for (int k0 = 0; k0 < K; k0 += 32) {
    gl2lds16(A + (size_t)(bm + row0) * K + k0 + kp, lA + c0 * 8);
    gl2lds16(A + (size_t)(bm + row0 + 64) * K + k0 + kp, lA + (c0 + 256) * 8);
    __syncthreads();
    bf16x8 af[2], bfr[3];
#pragma unroll
    for (int i = 0; i < 2; i++) af[i] = *(const bf16x8*)&lA[(wm + i * 16 + r) * 32 + q * 8];
#pragma unroll
    for (int j = 0; j < 3; j++) bfr[j] = *(const bf16x8*)&lW[(j * 16 + r) * K + k0 + q * 8];
#pragma unroll
    for (int i = 0; i < 2; i++)
#pragma unroll
      for (int j = 0; j < 3; j++)
        acc[i][j] = __builtin_amdgcn_mfma_f32_16x16x32_bf16(af[i], bfr[j], acc[i][j], 0, 0, 0);
    __syncthreads();
  }
#pragma unroll
  for (int i = 0; i < 2; i++)
#pragma unroll
    for (int j = 0; j < 3; j++)
#pragma unroll
      for (int t = 0; t < 4; t++)
        out[(size_t)(bm + wm + i * 16 + q * 4 + t) * 48 + j * 16 + r] = acc[i][j][t];
}

// =================== dt_proj (K=16) + softplus -> bf16 ===================
__global__ __launch_bounds__(256) void dtproj_kernel(const float* __restrict__ dbc,
                                                     const float* __restrict__ dtw,
                                                     const float* __restrict__ dtb,
                                                     bf16* __restrict__ dt) {
  __shared__ __align__(16) float sd[64 * 16];
  const int tid = threadIdx.x;
  const int p0 = blockIdx.x * 64;
  const int e = blockIdx.y * 256 + tid;
  {
    const int rowi = tid >> 2, coli = (tid & 3) * 4;
    *(float4*)&sd[rowi * 16 + coli] = *(const float4*)(dbc + (size_t)(p0 + rowi) * 48 + coli);
  }
  float w[16];
#pragma unroll
  for (int s = 0; s < 16; s += 4) {
    float4 t4 = *(const float4*)(dtw + (size_t)e * 16 + s);
    w[s] = t4.x; w[s + 1] = t4.y; w[s + 2] = t4.z; w[s + 3] = t4.w;
  }
  const float bias = dtb[e];
  __syncthreads();
  for (int p = 0; p < 64; p++) {
    float s = bias;
#pragma unroll
    for (int r2 = 0; r2 < 16; r2++) s += sd[p * 16 + r2] * w[r2];
    const float sp = (s > 15.f) ? s : __logf(1.f + __expf(s));
    dt[(size_t)(p0 + p) * DI + e] = (bf16)sp;
  }
}

// =================== scan pass1: per-chunk aggregates (U from h0=0, sum_dt) ===================
__global__ __launch_bounds__(256) void scan_pass1(const bf16* __restrict__ dt,
                                                  const bf16* __restrict__ xc,
                                                  const float* __restrict__ dbc,
                                                  const float* __restrict__ An,
                                                  float* __restrict__ U,
                                                  float* __restrict__ SD) {
  const int e = blockIdx.x * 256 + threadIdx.x;
  const int ch = blockIdx.y, b = blockIdx.z;
  float A[16], h[16];
#pragma unroll
  for (int s = 0; s < 16; s += 4) {
    float4 a4 = *(const float4*)(An + (size_t)e * 16 + s);
    A[s] = a4.x; A[s + 1] = a4.y; A[s + 2] = a4.z; A[s + 3] = a4.w;
  }
#pragma unroll
  for (int s = 0; s < 16; s++) h[s] = 0.f;
  float sdt = 0.f;
  const size_t posBase = (size_t)b * SEQ + (size_t)ch * CL;
  for (int il = 0; il < CL; il++) {
    const size_t pos = posBase + il;
    const float dtv = (float)dt[pos * DI + e];
    const float xv = (float)xc[pos * DI + e];
    const float* bc = dbc + pos * 48 + 16;
    float Bv[16];
#pragma unroll
    for (int s = 0; s < 16; s += 4) {
      float4 b4 = *(const float4*)(bc + s);
      Bv[s] = b4.x; Bv[s + 1] = b4.y; Bv[s + 2] = b4.z; Bv[s + 3] = b4.w;
    }
    const float dtx = dtv * xv;
    sdt += dtv;
#pragma unroll
    for (int s = 0; s < 16; s++) h[s] = __expf(dtv * A[s]) * h[s] + dtx * Bv[s];
  }
  float* up = U + ((size_t)(b * NC + ch) * DI + e) * 16;
#pragma unroll
  for (int s = 0; s < 16; s += 4) {
    float4 o; o.x = h[s]; o.y = h[s + 1]; o.z = h[s + 2]; o.w = h[s + 3];
    *(float4*)(up + s) = o;
  }
  SD[(size_t)(b * NC + ch) * DI + e] = sdt;
}

// =================== scan pass2: combine chunk aggregates, parallel over (b,e,s) ===================
// Chains are independent per state s -> 16x more threads than R1 version.
// U[c] := h0 entering chunk c (in-place exclusive scan).
__global__ __launch_bounds__(256) void scan_pass2(const float* __restrict__ SD,
                                                  float* U,
                                                  const float* __restrict__ An) {
  const int t = blockIdx.x * 256 + threadIdx.x;  // over BATCH*DI*16
  const int s = t & 15;
  const int e = (t >> 4) & (DI - 1);
  const int b = t >> 13;
  const float A = An[e * 16 + s];
  float h = 0.f;
  for (int c = 0; c < NC; c++) {
    const size_t cell = (size_t)(b * NC + c) * DI + e;
    const float sdv = SD[cell];             // broadcast across 16 s-threads
    const size_t base = cell * 16 + s;
    const float u = U[base];
    const float h0 = h;
    h = __expf(A * sdv) * h0 + u;
    U[base] = h0;
  }
}

// =================== scan pass3: replay chunk from true h0, emit gated y (yg aliases dt!) ===================
__global__ __launch_bounds__(256) void scan_pass3(const bf16* dt,
                                                  const bf16* __restrict__ xc,
                                                  const bf16* __restrict__ xz,
                                                  const float* __restrict__ dbc,
                                                  const float* __restrict__ An,
                                                  const float* __restrict__ H0,
                                                  const float* __restrict__ Dp,
                                                  bf16* yg) {
  const int e = blockIdx.x * 256 + threadIdx.x;
  const int ch = blockIdx.y, b = blockIdx.z;
  float A[16], h[16];
#pragma unroll
  for (int s = 0; s < 16; s += 4) {
    float4 a4 = *(const float4*)(An + (size_t)e * 16 + s);
    A[s] = a4.x; A[s + 1] = a4.y; A[s + 2] = a4.z; A[s + 3] = a4.w;
  }
  const float* hp = H0 + ((size_t)(b * NC + ch) * DI + e) * 16;
#pragma unroll
  for (int s = 0; s < 16; s += 4) {
    float4 h4 = *(const float4*)(hp + s);
    h[s] = h4.x; h[s + 1] = h4.y; h[s + 2] = h4.z; h[s + 3] = h4.w;
  }
  const float Dv = Dp[e];
  const size_t posBase = (size_t)b * SEQ + (size_t)ch * CL;
  for (int il = 0; il < CL; il++) {
    const size_t pos = posBase + il;
    const float dtv = (float)dt[pos * DI + e];
    const float xv = (float)xc[pos * DI + e];
    const float zv = (float)xz[pos * 1024 + DI + e];
    const float* bc = dbc + pos * 48 + 16;
    float Bv[16], Cv[16];
#pragma unroll
    for (int s = 0; s < 16; s += 4) {
      float4 b4 = *(const float4*)(bc + s);
      Bv[s] = b4.x; Bv[s + 1] = b4.y; Bv[s + 2] = b4.z; Bv[s + 3] = b4.w;
      float4 c4 = *(const float4*)(bc + 16 + s);
      Cv[s] = c4.x; Cv[s + 1] = c4.y; Cv[s + 2] = c4.z; Cv[s + 3] = c4.w;
    }
    const float dtx = dtv * xv;
    float y = 0.f;
#pragma unroll
    for (int s = 0; s < 16; s++) {
      h[s] = __expf(dtv * A[s]) * h[s] + dtx * Bv[s];
      y += h[s] * Cv[s];
    }
    const float yv = (y + Dv * xv) * zv * sigmoidf_(zv);
    yg[pos * DI + e] = (bf16)yv;  // same index this thread just read dt from — safe in-place
  }
}

// =================== host ===================
extern "C" void kernel_launch(void* const* d_in, const int* in_sizes, int n_in,
                              void* d_out, int out_size, void* d_ws, size_t ws_size,
                              hipStream_t stream) {
  const float* x = (const float*)d_in[0];
  const float* ln_w = (const float*)d_in[1];
  const float* ln_b = (const float*)d_in[2];
  const float* w_in = (const float*)d_in[3];
  const float* conv_w = (const float*)d_in[4];
  const float* conv_b = (const float*)d_in[5];
  const float* w_x = (const float*)d_in[6];
  const float* w_dt = (const float*)d_in[7];
  const float* b_dt = (const float*)d_in[8];
  const float* a_log = (const float*)d_in[9];
  const float* d_par = (const float*)d_in[10];
  const float* w_out = (const float*)d_in[11];

  char* ws = (char*)d_ws;
  size_t off = 0;
  auto alloc = [&](size_t bytes) {
    void* p = ws + off;
    off = (off + bytes + 255) & ~(size_t)255;
    return p;
  };
  bf16* xn = (bf16*)alloc((size_t)M * DM * 2);          // 16.8 MB
  bf16* xzb = (bf16*)alloc((size_t)M * 1024 * 2);       // 67.1 MB
  bf16* xcb = (bf16*)alloc((size_t)M * DI * 2);         // 33.6 MB
  float* dbc = (float*)alloc((size_t)M * 48 * 4);       // 6.3 MB
  bf16* dtb_ = (bf16*)alloc((size_t)M * DI * 2);        // 33.6 MB (becomes yg in pass3)
  float* U = (float*)alloc((size_t)BATCH * NC * DI * 16 * 4);  // 33.5 MB
  float* SD = (float*)alloc((size_t)BATCH * NC * DI * 4);      // 2.1 MB
  bf16* w1b = (bf16*)alloc(1024 * 256 * 2);
  bf16* wxb = (bf16*)alloc(48 * 512 * 2);
  bf16* wob = (bf16*)alloc(256 * 512 * 2);
  float* An = (float*)alloc(512 * 16 * 4);

  prep_kernel<<<dim3(1664), dim3(256), 0, stream>>>(w_in, w_x, w_out, a_log, w1b, wxb, wob, An);
  ln_kernel<<<dim3(M / 4), dim3(256), 0, stream>>>(x, ln_w, ln_b, xn);
  gemm_nt<1024, 256, true, false><<<dim3(M / 128, 8), dim3(256), 0, stream>>>(xn, w1b, (void*)xzb, nullptr);
  conv_silu<<<dim3((size_t)M * DI / 256), dim3(256), 0, stream>>>(xzb, conv_w, conv_b, xcb);
  gemm_xproj<<<dim3(M / 128), dim3(256), 0, stream>>>(xcb, wxb, dbc);
  dtproj_kernel<<<dim3(M / 64, 2), dim3(256), 0, stream>>>(dbc, w_dt, b_dt, dtb_);
  scan_pass1<<<dim3(2, NC, BATCH), dim3(256), 0, stream>>>(dtb_, xcb, dbc, An, U, SD);
  scan_pass2<<<dim3(BATCH * DI * 16 / 256), dim3(256), 0, stream>>>(SD, U, An);
  scan_pass3<<<dim3(2, NC, BATCH), dim3(256), 0, stream>>>(dtb_, xcb, xzb, dbc, An, U, d_par, dtb_);
  gemm_nt<256, 512, false, true><<<dim3(M / 128, 2), dim3(256), 0, stream>>>(dtb_, wob, d_out, x);
}

// Round 4
// 358.161 us; speedup vs baseline: 1.1545x; 1.0675x over previous
//
#include <hip/hip_runtime.h>
#include <cstdint>

#define DEVI __device__ __forceinline__

typedef __bf16 bf16;
typedef __bf16 bf16x8 __attribute__((ext_vector_type(8)));
typedef __bf16 bf16x4 __attribute__((ext_vector_type(4)));
typedef float floatx4 __attribute__((ext_vector_type(4)));

constexpr int BATCH = 16, SEQ = 2048, DM = 256, DI = 512;
constexpr int M = BATCH * SEQ;   // 32768 rows
constexpr int NC = 64;           // scan chunks per sequence
constexpr int CL = SEQ / NC;     // 32 steps per chunk
static_assert(NC * CL == SEQ, "chunking");
constexpr float LOG2E = 1.4426950408889634f;

// ---- async global->LDS (16B per lane, wave-uniform base + lane*16) ----
DEVI void gl2lds16(const void* g, void* l) {
  __builtin_amdgcn_global_load_lds(
      (const __attribute__((address_space(1))) unsigned int*)(uintptr_t)g,
      (__attribute__((address_space(3))) unsigned int*)(unsigned int)(uintptr_t)l,
      16, 0, 0);
}

DEVI float sigmoidf_(float x) { return 1.f / (1.f + __expf(-x)); }
// native v_exp_f32 (computes 2^x). NOTE: "__exp2f" collides with glibc math.h macros.
DEVI float exp2_(float x) { return __builtin_amdgcn_exp2f(x); }

// =================== prep: weights fp32 -> bf16, A2 = -exp(A_log)*log2e, power-law flag ===================
__global__ __launch_bounds__(256) void prep_kernel(
    const float* __restrict__ w1, const float* __restrict__ wx,
    const float* __restrict__ wo, const float* __restrict__ alog,
    bf16* __restrict__ w1b, bf16* __restrict__ wxb, bf16* __restrict__ wob,
    float* __restrict__ An, int* __restrict__ flags) {
  constexpr int n1 = 1024 * 256, n2 = 48 * 512, n3 = 256 * 512;
  int i = blockIdx.x * 256 + threadIdx.x;
  if (i < n1) w1b[i] = (bf16)w1[i];
  else if (i < n1 + n2) wxb[i - n1] = (bf16)wx[i - n1];
  else if (i < n1 + n2 + n3) wob[i - n1 - n2] = (bf16)wo[i - n1 - n2];
  else if (i < n1 + n2 + n3 + DI) {
    const int e = i - (n1 + n2 + n3);
    const float a0 = -__expf(alog[e * 16]);
    bool ok = (a0 < 0.f);
#pragma unroll 1
    for (int s = 0; s < 16; s++) {
      const float a = -__expf(alog[e * 16 + s]);
      An[e * 16 + s] = a * LOG2E;
      ok = ok && (__builtin_fabsf(a / a0 - (float)(s + 1)) < 1e-3f);
    }
    flags[e] = ok ? 1 : 0;
  }
}

// =================== LayerNorm: one wave per 256-col row, bf16 out ===================
__global__ __launch_bounds__(256) void ln_kernel(
    const float* __restrict__ x, const float* __restrict__ w,
    const float* __restrict__ b, bf16* __restrict__ xn) {
  const int row = blockIdx.x * 4 + (threadIdx.x >> 6);
  const int lane = threadIdx.x & 63;
  const float4 v = ((const float4*)(x + (size_t)row * DM))[lane];
  float s = v.x + v.y + v.z + v.w;
  float s2 = v.x * v.x + v.y * v.y + v.z * v.z + v.w * v.w;
#pragma unroll
  for (int m = 1; m < 64; m <<= 1) { s += __shfl_xor(s, m); s2 += __shfl_xor(s2, m); }
  const float mu = s * (1.f / DM);
  const float var = s2 * (1.f / DM) - mu * mu;
  const float rs = rsqrtf(var + 1e-5f);
  const float4 wv = ((const float4*)w)[lane];
  const float4 bv = ((const float4*)b)[lane];
  bf16x4 o;
  o[0] = (bf16)((v.x - mu) * rs * wv.x + bv.x);
  o[1] = (bf16)((v.y - mu) * rs * wv.y + bv.y);
  o[2] = (bf16)((v.z - mu) * rs * wv.z + bv.z);
  o[3] = (bf16)((v.w - mu) * rs * wv.w + bv.w);
  *(bf16x4*)(xn + (size_t)row * DM + lane * 4) = o;
}

// =================== NT bf16 GEMM: C[M,N] = A[M,K] * W[N,K]^T (m97 structure) ===================
template <int N, int K, bool OUT_BF16, bool RESID>
__global__ __launch_bounds__(256) void gemm_nt(const bf16* __restrict__ A,
                                               const bf16* __restrict__ W,
                                               void* __restrict__ out,
                                               const float* __restrict__ resid) {
  constexpr int BK = 32;
  __shared__ __align__(16) bf16 lA[128 * BK];
  __shared__ __align__(16) bf16 lB[128 * BK];
  const int tid = threadIdx.x;
  const int wave = tid >> 6, lane = tid & 63;
  const int bm = blockIdx.x * 128, bn = blockIdx.y * 128;
  const int wm = (wave >> 1) * 64, wn = (wave & 1) * 64;
  const int q = lane >> 4, r = lane & 15;
  floatx4 acc[4][4] = {};
  const int c0 = wave * 64 + lane;
  const int row0 = c0 >> 2, kp = (c0 & 3) * 8;
  for (int k0 = 0; k0 < K; k0 += BK) {
    gl2lds16(A + (size_t)(bm + row0) * K + k0 + kp, lA + c0 * 8);
    gl2lds16(A + (size_t)(bm + row0 + 64) * K + k0 + kp, lA + (c0 + 256) * 8);
    gl2lds16(W + (size_t)(bn + row0) * K + k0 + kp, lB + c0 * 8);
    gl2lds16(W + (size_t)(bn + row0 + 64) * K + k0 + kp, lB + (c0 + 256) * 8);
    __syncthreads();
    bf16x8 af[4], bfr[4];
#pragma unroll
    for (int i = 0; i < 4; i++) af[i] = *(const bf16x8*)&lA[(wm + i * 16 + r) * BK + q * 8];
#pragma unroll
    for (int j = 0; j < 4; j++) bfr[j] = *(const bf16x8*)&lB[(wn + j * 16 + r) * BK + q * 8];
#pragma unroll
    for (int i = 0; i < 4; i++)
#pragma unroll
      for (int j = 0; j < 4; j++)
        acc[i][j] = __builtin_amdgcn_mfma_f32_16x16x32_bf16(af[i], bfr[j], acc[i][j], 0, 0, 0);
    __syncthreads();
  }
#pragma unroll
  for (int i = 0; i < 4; i++)
#pragma unroll
    for (int j = 0; j < 4; j++)
#pragma unroll
      for (int t = 0; t < 4; t++) {
        const int row = bm + wm + i * 16 + q * 4 + t;
        const int col = bn + wn + j * 16 + r;
        const size_t idx = (size_t)row * N + col;
        float v = acc[i][j][t];
        if constexpr (OUT_BF16) {
          ((bf16*)out)[idx] = (bf16)v;
        } else {
          if constexpr (RESID) v += resid[idx];
          ((float*)out)[idx] = v;
        }
      }
}

// =================== causal depthwise conv(4) + SiLU — 8 e's per thread, bf16x8 loads ===================
__global__ __launch_bounds__(256) void conv_silu(const bf16* __restrict__ xz,
                                                 const float* __restrict__ cw,
                                                 const float* __restrict__ cb,
                                                 bf16* __restrict__ xc) {
  const int idx = blockIdx.x * 256 + threadIdx.x;  // over M*64
  const int eg = (idx & 63) * 8;
  const int pos = idx >> 6;          // one wave == one pos (branch below wave-uniform)
  const int l = pos & (SEQ - 1);
  float acc[8];
  {
    const float4 c0 = *(const float4*)(cb + eg);
    const float4 c1 = *(const float4*)(cb + eg + 4);
    acc[0] = c0.x; acc[1] = c0.y; acc[2] = c0.z; acc[3] = c0.w;
    acc[4] = c1.x; acc[5] = c1.y; acc[6] = c1.z; acc[7] = c1.w;
  }
  float w[8][4];
#pragma unroll
  for (int k = 0; k < 8; k++) {
    const float4 w4 = ((const float4*)cw)[eg + k];
    w[k][0] = w4.x; w[k][1] = w4.y; w[k][2] = w4.z; w[k][3] = w4.w;
  }
#pragma unroll
  for (int j = 0; j < 4; j++) {
    if (l - 3 + j >= 0) {
      const bf16x8 v = *(const bf16x8*)(xz + ((size_t)pos - (3 - j)) * 1024 + eg);
#pragma unroll
      for (int k = 0; k < 8; k++) acc[k] += (float)v[k] * w[k][j];
    }
  }
  bf16x8 o;
#pragma unroll
  for (int k = 0; k < 8; k++) { const float a = acc[k]; o[k] = (bf16)(a * sigmoidf_(a)); }
  *(bf16x8*)(xc + (size_t)pos * DI + eg) = o;
}

// =================== x_proj: dbc[M,48] = xc[M,512] * Wx[48,512]^T (W resident in LDS) ===================
__global__ __launch_bounds__(256) void gemm_xproj(const bf16* __restrict__ A,
                                                  const bf16* __restrict__ W,
                                                  float* __restrict__ out) {
  constexpr int K = DI;
  __shared__ __align__(16) bf16 lW[48 * K];
  __shared__ __align__(16) bf16 lA[128 * 32];
  const int tid = threadIdx.x;
  const int wave = tid >> 6, lane = tid & 63;
  const int bm = blockIdx.x * 128;
  const int q = lane >> 4, r = lane & 15;
#pragma unroll
  for (int rd = 0; rd < 12; rd++) {
    const int c = rd * 256 + tid;
    gl2lds16((const char*)W + (size_t)c * 16, (char*)lW + (size_t)c * 16);
  }
  const int c0 = wave * 64 + lane;
  const int row0 = c0 >> 2, kp = (c0 & 3) * 8;
  const int wm = wave * 32;
  floatx4 acc[2][3] = {};
  for (int k0 = 0; k0 < K; k0 += 32) {
    gl2lds16(A + (size_t)(bm + row0) * K + k0 + kp, lA + c0 * 8);
    gl2lds16(A + (size_t)(bm + row0 + 64) * K + k0 + kp, lA + (c0 + 256) * 8);
    __syncthreads();
    bf16x8 af[2], bfr[3];
#pragma unroll
    for (int i = 0; i < 2; i++) af[i] = *(const bf16x8*)&lA[(wm + i * 16 + r) * 32 + q * 8];
#pragma unroll
    for (int j = 0; j < 3; j++) bfr[j] = *(const bf16x8*)&lW[(j * 16 + r) * K + k0 + q * 8];
#pragma unroll
    for (int i = 0; i < 2; i++)
#pragma unroll
      for (int j = 0; j < 3; j++)
        acc[i][j] = __builtin_amdgcn_mfma_f32_16x16x32_bf16(af[i], bfr[j], acc[i][j], 0, 0, 0);
    __syncthreads();
  }
#pragma unroll
  for (int i = 0; i < 2; i++)
#pragma unroll
    for (int j = 0; j < 3; j++)
#pragma unroll
      for (int t = 0; t < 4; t++)
        out[(size_t)(bm + wm + i * 16 + q * 4 + t) * 48 + j * 16 + r] = acc[i][j][t];
}

// =================== dt_proj (K=16) + softplus -> bf16 ===================
__global__ __launch_bounds__(256) void dtproj_kernel(const float* __restrict__ dbc,
                                                     const float* __restrict__ dtw,
                                                     const float* __restrict__ dtb,
                                                     bf16* __restrict__ dt) {
  __shared__ __align__(16) float sd[64 * 16];
  const int tid = threadIdx.x;
  const int p0 = blockIdx.x * 64;
  const int e = blockIdx.y * 256 + tid;
  {
    const int rowi = tid >> 2, coli = (tid & 3) * 4;
    *(float4*)&sd[rowi * 16 + coli] = *(const float4*)(dbc + (size_t)(p0 + rowi) * 48 + coli);
  }
  float w[16];
#pragma unroll
  for (int s = 0; s < 16; s += 4) {
    float4 t4 = *(const float4*)(dtw + (size_t)e * 16 + s);
    w[s] = t4.x; w[s + 1] = t4.y; w[s + 2] = t4.z; w[s + 3] = t4.w;
  }
  const float bias = dtb[e];
  __syncthreads();
  for (int p = 0; p < 64; p++) {
    float s = bias;
#pragma unroll
    for (int r2 = 0; r2 < 16; r2++) s += sd[p * 16 + r2] * w[r2];
    const float sp = (s > 15.f) ? s : __logf(1.f + __expf(s));
    dt[(size_t)(p0 + p) * DI + e] = (bf16)sp;
  }
}

// =================== scan pass1: per-chunk aggregates (U from h0=0, sum_dt) ===================
// fast path (power-law A): 1 exp2 + serial power chain instead of 16 exp2 per step.
__global__ __launch_bounds__(256) void scan_pass1(const bf16* __restrict__ dt,
                                                  const bf16* __restrict__ xc,
                                                  const float* __restrict__ dbc,
                                                  const float* __restrict__ An,
                                                  const int* __restrict__ flags,
                                                  float* __restrict__ U,
                                                  float* __restrict__ SD) {
  const int e = blockIdx.x * 256 + threadIdx.x;
  const int ch = blockIdx.y, b = blockIdx.z;
  const int fast = flags[e];
  float h[16];
#pragma unroll
  for (int s = 0; s < 16; s++) h[s] = 0.f;
  float sdt = 0.f;
  const size_t posBase = (size_t)b * SEQ + (size_t)ch * CL;
  if (fast) {
    const float A0 = An[(size_t)e * 16];
    for (int il = 0; il < CL; il++) {
      const size_t pos = posBase + il;
      const float dtv = (float)dt[pos * DI + e];
      const float xv = (float)xc[pos * DI + e];
      const float* bc = dbc + pos * 48 + 16;   // wave-uniform -> s_load
      float Bv[16];
#pragma unroll
      for (int s = 0; s < 16; s += 4) {
        float4 b4 = *(const float4*)(bc + s);
        Bv[s] = b4.x; Bv[s + 1] = b4.y; Bv[s + 2] = b4.z; Bv[s + 3] = b4.w;
      }
      const float dtx = dtv * xv;
      sdt += dtv;
      const float d1 = exp2_(dtv * A0);
      float d = 1.f;
#pragma unroll
      for (int s = 0; s < 16; s++) { d *= d1; h[s] = d * h[s] + dtx * Bv[s]; }
    }
  } else {
    float A[16];
#pragma unroll
    for (int s = 0; s < 16; s += 4) {
      float4 a4 = *(const float4*)(An + (size_t)e * 16 + s);
      A[s] = a4.x; A[s + 1] = a4.y; A[s + 2] = a4.z; A[s + 3] = a4.w;
    }
    for (int il = 0; il < CL; il++) {
      const size_t pos = posBase + il;
      const float dtv = (float)dt[pos * DI + e];
      const float xv = (float)xc[pos * DI + e];
      const float* bc = dbc + pos * 48 + 16;
      float Bv[16];
#pragma unroll
      for (int s = 0; s < 16; s += 4) {
        float4 b4 = *(const float4*)(bc + s);
        Bv[s] = b4.x; Bv[s + 1] = b4.y; Bv[s + 2] = b4.z; Bv[s + 3] = b4.w;
      }
      const float dtx = dtv * xv;
      sdt += dtv;
#pragma unroll
      for (int s = 0; s < 16; s++) h[s] = exp2_(dtv * A[s]) * h[s] + dtx * Bv[s];
    }
  }
  float* up = U + ((size_t)(b * NC + ch) * DI + e) * 16;
#pragma unroll
  for (int s = 0; s < 16; s += 4) {
    float4 o; o.x = h[s]; o.y = h[s + 1]; o.z = h[s + 2]; o.w = h[s + 3];
    *(float4*)(up + s) = o;
  }
  SD[(size_t)(b * NC + ch) * DI + e] = sdt;
}

// =================== scan pass2: combine chunk aggregates, parallel over (b,e,s) ===================
__global__ __launch_bounds__(256) void scan_pass2(const float* __restrict__ SD,
                                                  float* U,
                                                  const float* __restrict__ An) {
  const int t = blockIdx.x * 256 + threadIdx.x;  // over BATCH*DI*16
  const int s = t & 15;
  const int e = (t >> 4) & (DI - 1);
  const int b = t >> 13;
  const float A = An[e * 16 + s];  // pre-scaled by log2e
  float h = 0.f;
  for (int c = 0; c < NC; c++) {
    const size_t cell = (size_t)(b * NC + c) * DI + e;
    const float sdv = SD[cell];
    const size_t base = cell * 16 + s;
    const float u = U[base];
    const float h0 = h;
    h = exp2_(A * sdv) * h0 + u;
    U[base] = h0;
  }
}

// =================== scan pass3: replay chunk from true h0, emit gated y (yg aliases dt!) ===================
__global__ __launch_bounds__(256) void scan_pass3(const bf16* dt,
                                                  const bf16* __restrict__ xc,
                                                  const bf16* __restrict__ xz,
                                                  const float* __restrict__ dbc,
                                                  const float* __restrict__ An,
                                                  const int* __restrict__ flags,
                                                  const float* __restrict__ H0,
                                                  const float* __restrict__ Dp,
                                                  bf16* yg) {
  const int e = blockIdx.x * 256 + threadIdx.x;
  const int ch = blockIdx.y, b = blockIdx.z;
  const int fast = flags[e];
  float h[16];
  const float* hp = H0 + ((size_t)(b * NC + ch) * DI + e) * 16;
#pragma unroll
  for (int s = 0; s < 16; s += 4) {
    float4 h4 = *(const float4*)(hp + s);
    h[s] = h4.x; h[s + 1] = h4.y; h[s + 2] = h4.z; h[s + 3] = h4.w;
  }
  const float Dv = Dp[e];
  const size_t posBase = (size_t)b * SEQ + (size_t)ch * CL;
  if (fast) {
    const float A0 = An[(size_t)e * 16];
    for (int il = 0; il < CL; il++) {
      const size_t pos = posBase + il;
      const float dtv = (float)dt[pos * DI + e];
      const float xv = (float)xc[pos * DI + e];
      const float zv = (float)xz[pos * 1024 + DI + e];
      const float* bc = dbc + pos * 48 + 16;
      float Bv[16], Cv[16];
#pragma unroll
      for (int s = 0; s < 16; s += 4) {
        float4 b4 = *(const float4*)(bc + s);
        Bv[s] = b4.x; Bv[s + 1] = b4.y; Bv[s + 2] = b4.z; Bv[s + 3] = b4.w;
        float4 c4 = *(const float4*)(bc + 16 + s);
        Cv[s] = c4.x; Cv[s + 1] = c4.y; Cv[s + 2] = c4.z; Cv[s + 3] = c4.w;
      }
      const float dtx = dtv * xv;
      const float d1 = exp2_(dtv * A0);
      float d = 1.f, y = 0.f;
#pragma unroll
      for (int s = 0; s < 16; s++) {
        d *= d1;
        h[s] = d * h[s] + dtx * Bv[s];
        y += h[s] * Cv[s];
      }
      const float yv = (y + Dv * xv) * zv * sigmoidf_(zv);
      yg[pos * DI + e] = (bf16)yv;
    }
  } else {
    float A[16];
#pragma unroll
    for (int s = 0; s < 16; s += 4) {
      float4 a4 = *(const float4*)(An + (size_t)e * 16 + s);
      A[s] = a4.x; A[s + 1] = a4.y; A[s + 2] = a4.z; A[s + 3] = a4.w;
    }
    for (int il = 0; il < CL; il++) {
      const size_t pos = posBase + il;
      const float dtv = (float)dt[pos * DI + e];
      const float xv = (float)xc[pos * DI + e];
      const float zv = (float)xz[pos * 1024 + DI + e];
      const float* bc = dbc + pos * 48 + 16;
      float Bv[16], Cv[16];
#pragma unroll
      for (int s = 0; s < 16; s += 4) {
        float4 b4 = *(const float4*)(bc + s);
        Bv[s] = b4.x; Bv[s + 1] = b4.y; Bv[s + 2] = b4.z; Bv[s + 3] = b4.w;
        float4 c4 = *(const float4*)(bc + 16 + s);
        Cv[s] = c4.x; Cv[s + 1] = c4.y; Cv[s + 2] = c4.z; Cv[s + 3] = c4.w;
      }
      const float dtx = dtv * xv;
      float y = 0.f;
#pragma unroll
      for (int s = 0; s < 16; s++) {
        h[s] = exp2_(dtv * A[s]) * h[s] + dtx * Bv[s];
        y += h[s] * Cv[s];
      }
      const float yv = (y + Dv * xv) * zv * sigmoidf_(zv);
      yg[pos * DI + e] = (bf16)yv;
    }
  }
}

// =================== host ===================
extern "C" void kernel_launch(void* const* d_in, const int* in_sizes, int n_in,
                              void* d_out, int out_size, void* d_ws, size_t ws_size,
                              hipStream_t stream) {
  const float* x = (const float*)d_in[0];
  const float* ln_w = (const float*)d_in[1];
  const float* ln_b = (const float*)d_in[2];
  const float* w_in = (const float*)d_in[3];
  const float* conv_w = (const float*)d_in[4];
  const float* conv_b = (const float*)d_in[5];
  const float* w_x = (const float*)d_in[6];
  const float* w_dt = (const float*)d_in[7];
  const float* b_dt = (const float*)d_in[8];
  const float* a_log = (const float*)d_in[9];
  const float* d_par = (const float*)d_in[10];
  const float* w_out = (const float*)d_in[11];

  char* ws = (char*)d_ws;
  size_t off = 0;
  auto alloc = [&](size_t bytes) {
    void* p = ws + off;
    off = (off + bytes + 255) & ~(size_t)255;
    return p;
  };
  bf16* xn = (bf16*)alloc((size_t)M * DM * 2);
  bf16* xzb = (bf16*)alloc((size_t)M * 1024 * 2);
  bf16* xcb = (bf16*)alloc((size_t)M * DI * 2);
  float* dbc = (float*)alloc((size_t)M * 48 * 4);
  bf16* dtb_ = (bf16*)alloc((size_t)M * DI * 2);
  float* U = (float*)alloc((size_t)BATCH * NC * DI * 16 * 4);
  float* SD = (float*)alloc((size_t)BATCH * NC * DI * 4);
  bf16* w1b = (bf16*)alloc(1024 * 256 * 2);
  bf16* wxb = (bf16*)alloc(48 * 512 * 2);
  bf16* wob = (bf16*)alloc(256 * 512 * 2);
  float* An = (float*)alloc(512 * 16 * 4);
  int* flags = (int*)alloc(512 * 4);

  constexpr int prep_n = 1024 * 256 + 48 * 512 + 256 * 512 + DI;
  prep_kernel<<<dim3((prep_n + 255) / 256), dim3(256), 0, stream>>>(w_in, w_x, w_out, a_log, w1b, wxb, wob, An, flags);
  ln_kernel<<<dim3(M / 4), dim3(256), 0, stream>>>(x, ln_w, ln_b, xn);
  gemm_nt<1024, 256, true, false><<<dim3(M / 128, 8), dim3(256), 0, stream>>>(xn, w1b, (void*)xzb, nullptr);
  conv_silu<<<dim3(M * 64 / 256), dim3(256), 0, stream>>>(xzb, conv_w, conv_b, xcb);
  gemm_xproj<<<dim3(M / 128), dim3(256), 0, stream>>>(xcb, wxb, dbc);
  dtproj_kernel<<<dim3(M / 64, 2), dim3(256), 0, stream>>>(dbc, w_dt, b_dt, dtb_);
  scan_pass1<<<dim3(2, NC, BATCH), dim3(256), 0, stream>>>(dtb_, xcb, dbc, An, flags, U, SD);
  scan_pass2<<<dim3(BATCH * DI * 16 / 256), dim3(256), 0, stream>>>(SD, U, An);
  scan_pass3<<<dim3(2, NC, BATCH), dim3(256), 0, stream>>>(dtb_, xcb, xzb, dbc, An, flags, U, d_par, dtb_);
  gemm_nt<256, 512, false, true><<<dim3(M / 128, 2), dim3(256), 0, stream>>>(dtb_, wob, d_out, x);
}

// Round 5
// 307.374 us; speedup vs baseline: 1.3453x; 1.1652x over previous
//
#include <hip/hip_runtime.h>
#include <cstdint>

#define DEVI __device__ __forceinline__

typedef __bf16 bf16;
typedef __bf16 bf16x8 __attribute__((ext_vector_type(8)));
typedef __bf16 bf16x4 __attribute__((ext_vector_type(4)));
typedef __bf16 bf16x2 __attribute__((ext_vector_type(2)));
typedef float floatx4 __attribute__((ext_vector_type(4)));

constexpr int BATCH = 16, SEQ = 2048, DM = 256, DI = 512;
constexpr int M = BATCH * SEQ;   // 32768 rows
constexpr int NC = 64;           // scan chunks per sequence
constexpr int CL = SEQ / NC;     // 32 steps per chunk
static_assert(NC * CL == SEQ, "chunking");
constexpr float LOG2E = 1.4426950408889634f;

// ---- async global->LDS (16B per lane, wave-uniform base + lane*16) ----
DEVI void gl2lds16(const void* g, void* l) {
  __builtin_amdgcn_global_load_lds(
      (const __attribute__((address_space(1))) unsigned int*)(uintptr_t)g,
      (__attribute__((address_space(3))) unsigned int*)(unsigned int)(uintptr_t)l,
      16, 0, 0);
}

DEVI float sigmoidf_(float x) { return 1.f / (1.f + __expf(-x)); }
// native v_exp_f32 (computes 2^x). NOTE: "__exp2f" collides with glibc math.h macros.
DEVI float exp2_(float x) { return __builtin_amdgcn_exp2f(x); }

// =================== prep: weights fp32 -> bf16, A2 = -exp(A_log)*log2e, power-law flag ===================
__global__ __launch_bounds__(256) void prep_kernel(
    const float* __restrict__ w1, const float* __restrict__ wx,
    const float* __restrict__ wo, const float* __restrict__ alog,
    bf16* __restrict__ w1b, bf16* __restrict__ wxb, bf16* __restrict__ wob,
    float* __restrict__ An, int* __restrict__ flags) {
  constexpr int n1 = 1024 * 256, n2 = 48 * 512, n3 = 256 * 512;
  int i = blockIdx.x * 256 + threadIdx.x;
  if (i < n1) w1b[i] = (bf16)w1[i];
  else if (i < n1 + n2) wxb[i - n1] = (bf16)wx[i - n1];
  else if (i < n1 + n2 + n3) wob[i - n1 - n2] = (bf16)wo[i - n1 - n2];
  else if (i < n1 + n2 + n3 + DI) {
    const int e = i - (n1 + n2 + n3);
    const float a0 = -__expf(alog[e * 16]);
    bool ok = (a0 < 0.f);
#pragma unroll 1
    for (int s = 0; s < 16; s++) {
      const float a = -__expf(alog[e * 16 + s]);
      An[e * 16 + s] = a * LOG2E;
      ok = ok && (__builtin_fabsf(a / a0 - (float)(s + 1)) < 1e-3f);
    }
    flags[e] = ok ? 1 : 0;
  }
}

// =================== LayerNorm: one wave per 256-col row, bf16 out ===================
__global__ __launch_bounds__(256) void ln_kernel(
    const float* __restrict__ x, const float* __restrict__ w,
    const float* __restrict__ b, bf16* __restrict__ xn) {
  const int row = blockIdx.x * 4 + (threadIdx.x >> 6);
  const int lane = threadIdx.x & 63;
  const float4 v = ((const float4*)(x + (size_t)row * DM))[lane];
  float s = v.x + v.y + v.z + v.w;
  float s2 = v.x * v.x + v.y * v.y + v.z * v.z + v.w * v.w;
#pragma unroll
  for (int m = 1; m < 64; m <<= 1) { s += __shfl_xor(s, m); s2 += __shfl_xor(s2, m); }
  const float mu = s * (1.f / DM);
  const float var = s2 * (1.f / DM) - mu * mu;
  const float rs = rsqrtf(var + 1e-5f);
  const float4 wv = ((const float4*)w)[lane];
  const float4 bv = ((const float4*)b)[lane];
  bf16x4 o;
  o[0] = (bf16)((v.x - mu) * rs * wv.x + bv.x);
  o[1] = (bf16)((v.y - mu) * rs * wv.y + bv.y);
  o[2] = (bf16)((v.z - mu) * rs * wv.z + bv.z);
  o[3] = (bf16)((v.w - mu) * rs * wv.w + bv.w);
  *(bf16x4*)(xn + (size_t)row * DM + lane * 4) = o;
}

// =================== NT bf16 GEMM: C[M,N] = A[M,K] * W[N,K]^T (m97 structure) ===================
template <int N, int K, bool OUT_BF16, bool RESID>
__global__ __launch_bounds__(256) void gemm_nt(const bf16* __restrict__ A,
                                               const bf16* __restrict__ W,
                                               void* __restrict__ out,
                                               const float* __restrict__ resid) {
  constexpr int BK = 32;
  __shared__ __align__(16) bf16 lA[128 * BK];
  __shared__ __align__(16) bf16 lB[128 * BK];
  const int tid = threadIdx.x;
  const int wave = tid >> 6, lane = tid & 63;
  const int bm = blockIdx.x * 128, bn = blockIdx.y * 128;
  const int wm = (wave >> 1) * 64, wn = (wave & 1) * 64;
  const int q = lane >> 4, r = lane & 15;
  floatx4 acc[4][4] = {};
  const int c0 = wave * 64 + lane;
  const int row0 = c0 >> 2, kp = (c0 & 3) * 8;
  for (int k0 = 0; k0 < K; k0 += BK) {
    gl2lds16(A + (size_t)(bm + row0) * K + k0 + kp, lA + c0 * 8);
    gl2lds16(A + (size_t)(bm + row0 + 64) * K + k0 + kp, lA + (c0 + 256) * 8);
    gl2lds16(W + (size_t)(bn + row0) * K + k0 + kp, lB + c0 * 8);
    gl2lds16(W + (size_t)(bn + row0 + 64) * K + k0 + kp, lB + (c0 + 256) * 8);
    __syncthreads();
    bf16x8 af[4], bfr[4];
#pragma unroll
    for (int i = 0; i < 4; i++) af[i] = *(const bf16x8*)&lA[(wm + i * 16 + r) * BK + q * 8];
#pragma unroll
    for (int j = 0; j < 4; j++) bfr[j] = *(const bf16x8*)&lB[(wn + j * 16 + r) * BK + q * 8];
#pragma unroll
    for (int i = 0; i < 4; i++)
#pragma unroll
      for (int j = 0; j < 4; j++)
        acc[i][j] = __builtin_amdgcn_mfma_f32_16x16x32_bf16(af[i], bfr[j], acc[i][j], 0, 0, 0);
    __syncthreads();
  }
#pragma unroll
  for (int i = 0; i < 4; i++)
#pragma unroll
    for (int j = 0; j < 4; j++)
#pragma unroll
      for (int t = 0; t < 4; t++) {
        const int row = bm + wm + i * 16 + q * 4 + t;
        const int col = bn + wn + j * 16 + r;
        const size_t idx = (size_t)row * N + col;
        float v = acc[i][j][t];
        if constexpr (OUT_BF16) {
          ((bf16*)out)[idx] = (bf16)v;
        } else {
          if constexpr (RESID) v += resid[idx];
          ((float*)out)[idx] = v;
        }
      }
}

// =================== causal depthwise conv(4) + SiLU ===================
// R5: thread = 2 adjacent e (packed 4B coalesced loads), 8 positions/thread
// (sliding window). Weight loads amortized 8x; all global traffic coalesced.
__global__ __launch_bounds__(256) void conv_silu(const bf16* __restrict__ xz,
                                                 const float* __restrict__ cw,
                                                 const float* __restrict__ cb,
                                                 bf16* __restrict__ xc) {
  const int tid = threadIdx.x;
  const int e2 = tid * 2;              // [0,512) in steps of 2
  const int p0 = blockIdx.x * 8;
  const int b = blockIdx.y;
  const float4 w0 = ((const float4*)cw)[e2];
  const float4 w1 = ((const float4*)cw)[e2 + 1];
  const float2 bias = *(const float2*)(cb + e2);
  float xa[11], xb_[11];
#pragma unroll
  for (int j = 0; j < 11; j++) {
    const int pos = p0 - 3 + j;
    float fa = 0.f, fb = 0.f;
    if (pos >= 0) {  // block-uniform (only blockIdx.x==0 has pos<0)
      const unsigned u = *(const unsigned*)(xz + ((size_t)b * SEQ + pos) * 1024 + e2);
      fa = __uint_as_float(u << 16);
      fb = __uint_as_float(u & 0xFFFF0000u);
    }
    xa[j] = fa; xb_[j] = fb;
  }
#pragma unroll
  for (int k = 0; k < 8; k++) {
    const float a0 = bias.x + xa[k] * w0.x + xa[k + 1] * w0.y + xa[k + 2] * w0.z + xa[k + 3] * w0.w;
    const float a1 = bias.y + xb_[k] * w1.x + xb_[k + 1] * w1.y + xb_[k + 2] * w1.z + xb_[k + 3] * w1.w;
    bf16x2 o;
    o[0] = (bf16)(a0 * sigmoidf_(a0));
    o[1] = (bf16)(a1 * sigmoidf_(a1));
    *(bf16x2*)(xc + ((size_t)b * SEQ + p0 + k) * DI + e2) = o;
  }
}

// =================== x_proj: dbc[M,48] = xc[M,512] * Wx[48,512]^T (W resident in LDS) ===================
__global__ __launch_bounds__(256) void gemm_xproj(const bf16* __restrict__ A,
                                                  const bf16* __restrict__ W,
                                                  float* __restrict__ out) {
  constexpr int K = DI;
  __shared__ __align__(16) bf16 lW[48 * K];
  __shared__ __align__(16) bf16 lA[128 * 32];
  const int tid = threadIdx.x;
  const int wave = tid >> 6, lane = tid & 63;
  const int bm = blockIdx.x * 128;
  const int q = lane >> 4, r = lane & 15;
#pragma unroll
  for (int rd = 0; rd < 12; rd++) {
    const int c = rd * 256 + tid;
    gl2lds16((const char*)W + (size_t)c * 16, (char*)lW + (size_t)c * 16);
  }
  const int c0 = wave * 64 + lane;
  const int row0 = c0 >> 2, kp = (c0 & 3) * 8;
  const int wm = wave * 32;
  floatx4 acc[2][3] = {};
  for (int k0 = 0; k0 < K; k0 += 32) {
    gl2lds16(A + (size_t)(bm + row0) * K + k0 + kp, lA + c0 * 8);
    gl2lds16(A + (size_t)(bm + row0 + 64) * K + k0 + kp, lA + (c0 + 256) * 8);
    __syncthreads();
    bf16x8 af[2], bfr[3];
#pragma unroll
    for (int i = 0; i < 2; i++) af[i] = *(const bf16x8*)&lA[(wm + i * 16 + r) * 32 + q * 8];
#pragma unroll
    for (int j = 0; j < 3; j++) bfr[j] = *(const bf16x8*)&lW[(j * 16 + r) * K + k0 + q * 8];
#pragma unroll
    for (int i = 0; i < 2; i++)
#pragma unroll
      for (int j = 0; j < 3; j++)
        acc[i][j] = __builtin_amdgcn_mfma_f32_16x16x32_bf16(af[i], bfr[j], acc[i][j], 0, 0, 0);
    __syncthreads();
  }
#pragma unroll
  for (int i = 0; i < 2; i++)
#pragma unroll
    for (int j = 0; j < 3; j++)
#pragma unroll
      for (int t = 0; t < 4; t++)
        out[(size_t)(bm + wm + i * 16 + q * 4 + t) * 48 + j * 16 + r] = acc[i][j][t];
}

// =================== dt_proj (K=16) + softplus -> bf16 ===================
__global__ __launch_bounds__(256) void dtproj_kernel(const float* __restrict__ dbc,
                                                     const float* __restrict__ dtw,
                                                     const float* __restrict__ dtb,
                                                     bf16* __restrict__ dt) {
  __shared__ __align__(16) float sd[64 * 16];
  const int tid = threadIdx.x;
  const int p0 = blockIdx.x * 64;
  const int e = blockIdx.y * 256 + tid;
  {
    const int rowi = tid >> 2, coli = (tid & 3) * 4;
    *(float4*)&sd[rowi * 16 + coli] = *(const float4*)(dbc + (size_t)(p0 + rowi) * 48 + coli);
  }
  float w[16];
#pragma unroll
  for (int s = 0; s < 16; s += 4) {
    float4 t4 = *(const float4*)(dtw + (size_t)e * 16 + s);
    w[s] = t4.x; w[s + 1] = t4.y; w[s + 2] = t4.z; w[s + 3] = t4.w;
  }
  const float bias = dtb[e];
  __syncthreads();
  for (int p = 0; p < 64; p++) {
    float s = bias;
#pragma unroll
    for (int r2 = 0; r2 < 16; r2++) s += sd[p * 16 + r2] * w[r2];
    const float sp = (s > 15.f) ? s : __logf(1.f + __expf(s));
    dt[(size_t)(p0 + p) * DI + e] = (bf16)sp;
  }
}

// =================== scan pass1: per-chunk aggregates (U from h0=0, sum_dt) ===================
// fast path (power-law A): 1 exp2 + serial power chain instead of 16 exp2 per step.
__global__ __launch_bounds__(256) void scan_pass1(const bf16* __restrict__ dt,
                                                  const bf16* __restrict__ xc,
                                                  const float* __restrict__ dbc,
                                                  const float* __restrict__ An,
                                                  const int* __restrict__ flags,
                                                  float* __restrict__ U,
                                                  float* __restrict__ SD) {
  const int e = blockIdx.x * 256 + threadIdx.x;
  const int ch = blockIdx.y, b = blockIdx.z;
  const int fast = flags[e];
  float h[16];
#pragma unroll
  for (int s = 0; s < 16; s++) h[s] = 0.f;
  float sdt = 0.f;
  const size_t posBase = (size_t)b * SEQ + (size_t)ch * CL;
  if (fast) {
    const float A0 = An[(size_t)e * 16];
    for (int il = 0; il < CL; il++) {
      const size_t pos = posBase + il;
      const float dtv = (float)dt[pos * DI + e];
      const float xv = (float)xc[pos * DI + e];
      const float* bc = dbc + pos * 48 + 16;   // wave-uniform -> s_load
      float Bv[16];
#pragma unroll
      for (int s = 0; s < 16; s += 4) {
        float4 b4 = *(const float4*)(bc + s);
        Bv[s] = b4.x; Bv[s + 1] = b4.y; Bv[s + 2] = b4.z; Bv[s + 3] = b4.w;
      }
      const float dtx = dtv * xv;
      sdt += dtv;
      const float d1 = exp2_(dtv * A0);
      float d = 1.f;
#pragma unroll
      for (int s = 0; s < 16; s++) { d *= d1; h[s] = d * h[s] + dtx * Bv[s]; }
    }
  } else {
    float A[16];
#pragma unroll
    for (int s = 0; s < 16; s += 4) {
      float4 a4 = *(const float4*)(An + (size_t)e * 16 + s);
      A[s] = a4.x; A[s + 1] = a4.y; A[s + 2] = a4.z; A[s + 3] = a4.w;
    }
    for (int il = 0; il < CL; il++) {
      const size_t pos = posBase + il;
      const float dtv = (float)dt[pos * DI + e];
      const float xv = (float)xc[pos * DI + e];
      const float* bc = dbc + pos * 48 + 16;
      float Bv[16];
#pragma unroll
      for (int s = 0; s < 16; s += 4) {
        float4 b4 = *(const float4*)(bc + s);
        Bv[s] = b4.x; Bv[s + 1] = b4.y; Bv[s + 2] = b4.z; Bv[s + 3] = b4.w;
      }
      const float dtx = dtv * xv;
      sdt += dtv;
#pragma unroll
      for (int s = 0; s < 16; s++) h[s] = exp2_(dtv * A[s]) * h[s] + dtx * Bv[s];
    }
  }
  float* up = U + ((size_t)(b * NC + ch) * DI + e) * 16;
#pragma unroll
  for (int s = 0; s < 16; s += 4) {
    float4 o; o.x = h[s]; o.y = h[s + 1]; o.z = h[s + 2]; o.w = h[s + 3];
    *(float4*)(up + s) = o;
  }
  SD[(size_t)(b * NC + ch) * DI + e] = sdt;
}

// =================== scan pass2: combine chunk aggregates, parallel over (b,e,s) ===================
__global__ __launch_bounds__(256) void scan_pass2(const float* __restrict__ SD,
                                                  float* U,
                                                  const float* __restrict__ An) {
  const int t = blockIdx.x * 256 + threadIdx.x;  // over BATCH*DI*16
  const int s = t & 15;
  const int e = (t >> 4) & (DI - 1);
  const int b = t >> 13;
  const float A = An[e * 16 + s];  // pre-scaled by log2e
  float h = 0.f;
  for (int c = 0; c < NC; c++) {
    const size_t cell = (size_t)(b * NC + c) * DI + e;
    const float sdv = SD[cell];
    const size_t base = cell * 16 + s;
    const float u = U[base];
    const float h0 = h;
    h = exp2_(A * sdv) * h0 + u;
    U[base] = h0;
  }
}

// =================== scan pass3: replay chunk from true h0, emit gated y (yg aliases dt!) ===================
__global__ __launch_bounds__(256) void scan_pass3(const bf16* dt,
                                                  const bf16* __restrict__ xc,
                                                  const bf16* __restrict__ xz,
                                                  const float* __restrict__ dbc,
                                                  const float* __restrict__ An,
                                                  const int* __restrict__ flags,
                                                  const float* __restrict__ H0,
                                                  const float* __restrict__ Dp,
                                                  bf16* yg) {
  const int e = blockIdx.x * 256 + threadIdx.x;
  const int ch = blockIdx.y, b = blockIdx.z;
  const int fast = flags[e];
  float h[16];
  const float* hp = H0 + ((size_t)(b * NC + ch) * DI + e) * 16;
#pragma unroll
  for (int s = 0; s < 16; s += 4) {
    float4 h4 = *(const float4*)(hp + s);
    h[s] = h4.x; h[s + 1] = h4.y; h[s + 2] = h4.z; h[s + 3] = h4.w;
  }
  const float Dv = Dp[e];
  const size_t posBase = (size_t)b * SEQ + (size_t)ch * CL;
  if (fast) {
    const float A0 = An[(size_t)e * 16];
    for (int il = 0; il < CL; il++) {
      const size_t pos = posBase + il;
      const float dtv = (float)dt[pos * DI + e];
      const float xv = (float)xc[pos * DI + e];
      const float zv = (float)xz[pos * 1024 + DI + e];
      const float* bc = dbc + pos * 48 + 16;
      float Bv[16], Cv[16];
#pragma unroll
      for (int s = 0; s < 16; s += 4) {
        float4 b4 = *(const float4*)(bc + s);
        Bv[s] = b4.x; Bv[s + 1] = b4.y; Bv[s + 2] = b4.z; Bv[s + 3] = b4.w;
        float4 c4 = *(const float4*)(bc + 16 + s);
        Cv[s] = c4.x; Cv[s + 1] = c4.y; Cv[s + 2] = c4.z; Cv[s + 3] = c4.w;
      }
      const float dtx = dtv * xv;
      const float d1 = exp2_(dtv * A0);
      float d = 1.f, y = 0.f;
#pragma unroll
      for (int s = 0; s < 16; s++) {
        d *= d1;
        h[s] = d * h[s] + dtx * Bv[s];
        y += h[s] * Cv[s];
      }
      const float yv = (y + Dv * xv) * zv * sigmoidf_(zv);
      yg[pos * DI + e] = (bf16)yv;
    }
  } else {
    float A[16];
#pragma unroll
    for (int s = 0; s < 16; s += 4) {
      float4 a4 = *(const float4*)(An + (size_t)e * 16 + s);
      A[s] = a4.x; A[s + 1] = a4.y; A[s + 2] = a4.z; A[s + 3] = a4.w;
    }
    for (int il = 0; il < CL; il++) {
      const size_t pos = posBase + il;
      const float dtv = (float)dt[pos * DI + e];
      const float xv = (float)xc[pos * DI + e];
      const float zv = (float)xz[pos * 1024 + DI + e];
      const float* bc = dbc + pos * 48 + 16;
      float Bv[16], Cv[16];
#pragma unroll
      for (int s = 0; s < 16; s += 4) {
        float4 b4 = *(const float4*)(bc + s);
        Bv[s] = b4.x; Bv[s + 1] = b4.y; Bv[s + 2] = b4.z; Bv[s + 3] = b4.w;
        float4 c4 = *(const float4*)(bc + 16 + s);
        Cv[s] = c4.x; Cv[s + 1] = c4.y; Cv[s + 2] = c4.z; Cv[s + 3] = c4.w;
      }
      const float dtx = dtv * xv;
      float y = 0.f;
#pragma unroll
      for (int s = 0; s < 16; s++) {
        h[s] = exp2_(dtv * A[s]) * h[s] + dtx * Bv[s];
        y += h[s] * Cv[s];
      }
      const float yv = (y + Dv * xv) * zv * sigmoidf_(zv);
      yg[pos * DI + e] = (bf16)yv;
    }
  }
}

// =================== host ===================
extern "C" void kernel_launch(void* const* d_in, const int* in_sizes, int n_in,
                              void* d_out, int out_size, void* d_ws, size_t ws_size,
                              hipStream_t stream) {
  const float* x = (const float*)d_in[0];
  const float* ln_w = (const float*)d_in[1];
  const float* ln_b = (const float*)d_in[2];
  const float* w_in = (const float*)d_in[3];
  const float* conv_w = (const float*)d_in[4];
  const float* conv_b = (const float*)d_in[5];
  const float* w_x = (const float*)d_in[6];
  const float* w_dt = (const float*)d_in[7];
  const float* b_dt = (const float*)d_in[8];
  const float* a_log = (const float*)d_in[9];
  const float* d_par = (const float*)d_in[10];
  const float* w_out = (const float*)d_in[11];

  char* ws = (char*)d_ws;
  size_t off = 0;
  auto alloc = [&](size_t bytes) {
    void* p = ws + off;
    off = (off + bytes + 255) & ~(size_t)255;
    return p;
  };
  bf16* xn = (bf16*)alloc((size_t)M * DM * 2);
  bf16* xzb = (bf16*)alloc((size_t)M * 1024 * 2);
  bf16* xcb = (bf16*)alloc((size_t)M * DI * 2);
  float* dbc = (float*)alloc((size_t)M * 48 * 4);
  bf16* dtb_ = (bf16*)alloc((size_t)M * DI * 2);
  float* U = (float*)alloc((size_t)BATCH * NC * DI * 16 * 4);
  float* SD = (float*)alloc((size_t)BATCH * NC * DI * 4);
  bf16* w1b = (bf16*)alloc(1024 * 256 * 2);
  bf16* wxb = (bf16*)alloc(48 * 512 * 2);
  bf16* wob = (bf16*)alloc(256 * 512 * 2);
  float* An = (float*)alloc(512 * 16 * 4);
  int* flags = (int*)alloc(512 * 4);

  constexpr int prep_n = 1024 * 256 + 48 * 512 + 256 * 512 + DI;
  prep_kernel<<<dim3((prep_n + 255) / 256), dim3(256), 0, stream>>>(w_in, w_x, w_out, a_log, w1b, wxb, wob, An, flags);
  ln_kernel<<<dim3(M / 4), dim3(256), 0, stream>>>(x, ln_w, ln_b, xn);
  gemm_nt<1024, 256, true, false><<<dim3(M / 128, 8), dim3(256), 0, stream>>>(xn, w1b, (void*)xzb, nullptr);
  conv_silu<<<dim3(SEQ / 8, BATCH), dim3(256), 0, stream>>>(xzb, conv_w, conv_b, xcb);
  gemm_xproj<<<dim3(M / 128), dim3(256), 0, stream>>>(xcb, wxb, dbc);
  dtproj_kernel<<<dim3(M / 64, 2), dim3(256), 0, stream>>>(dbc, w_dt, b_dt, dtb_);
  scan_pass1<<<dim3(2, NC, BATCH), dim3(256), 0, stream>>>(dtb_, xcb, dbc, An, flags, U, SD);
  scan_pass2<<<dim3(BATCH * DI * 16 / 256), dim3(256), 0, stream>>>(SD, U, An);
  scan_pass3<<<dim3(2, NC, BATCH), dim3(256), 0, stream>>>(dtb_, xcb, xzb, dbc, An, flags, U, d_par, dtb_);
  gemm_nt<256, 512, false, true><<<dim3(M / 128, 2), dim3(256), 0, stream>>>(dtb_, wob, d_out, x);
}